// Round 1
// baseline (2081.270 us; speedup 1.0000x reference)
//
#include <hip/hip_runtime.h>
#include <math.h>

// Problem constants (fixed by reference):
//   x: [T=12, B=16, N=2048, D=128] fp32; F = T*D = 1536; K = 5
//   out: [B, N, N] fp32 = 16 * 2048 * 2048 = 67108864 elements
#define TT 12
#define BB 16
#define NN 2048
#define DD 128
#define KTOP 5
#define NROWS (BB * NN)          // 32768
#define NTILE 32                 // N / 64
#define NTRI  528                // 32*33/2 upper-tri tiles per batch

// ---------------- stable top-k helpers (match lax.top_k: desc value, ties -> lowest index)
__device__ __forceinline__ bool tk_better(float v1, int i1, float v2, int i2) {
    return (v1 > v2) || (v1 == v2 && i1 < i2);
}

__device__ __forceinline__ void tk_insert(float bv[KTOP], int bi[KTOP], float v, int idx) {
    if (!tk_better(v, idx, bv[KTOP - 1], bi[KTOP - 1])) return;
    bv[KTOP - 1] = v; bi[KTOP - 1] = idx;
#pragma unroll
    for (int k = KTOP - 1; k > 0; --k) {
        if (tk_better(bv[k], bi[k], bv[k - 1], bi[k - 1])) {
            float tv = bv[k]; bv[k] = bv[k - 1]; bv[k - 1] = tv;
            int tx = bi[k]; bi[k] = bi[k - 1]; bi[k - 1] = tx;
        }
    }
}

// ---------------- 1) inverse L2 norm per (b,n) row: one wave per row
__global__ __launch_bounds__(256) void norms_kernel(const float* __restrict__ x,
                                                    float* __restrict__ invn) {
    int lane = threadIdx.x & 63;
    int row  = (blockIdx.x << 2) + (threadIdx.x >> 6);   // 4 waves/block
    int b = row >> 11;
    int n = row & (NN - 1);
    float s = 0.0f;
#pragma unroll
    for (int i = 0; i < 6; ++i) {                // 6 * 64 lanes * 4 floats = 1536
        int e = (lane + (i << 6)) << 2;          // float index in [0,1536), mult of 4
        int t = e >> 7;                          // which T chunk
        int d = e & 127;
        const float4 v = *(const float4*)(x + ((((size_t)t * BB + b) * NN + n) << 7) + d);
        s += v.x * v.x + v.y * v.y + v.z * v.z + v.w * v.w;
    }
#pragma unroll
    for (int off = 32; off; off >>= 1) s += __shfl_down(s, off);
    if (lane == 0) invn[row] = 1.0f / sqrtf(s);
}

// ---------------- 2) fp32 Gram GEMM, upper-tri 64x64 tiles, write tile + transpose
// dist[b][n][m] = dot(f_n, f_m) * invn[n] * invn[m], written into d_out as scratch.
__global__ __launch_bounds__(256) void gemm_kernel(const float* __restrict__ x,
                                                   const float* __restrict__ invn,
                                                   float* __restrict__ dist) {
    __shared__ float As[32][68];   // k-major, pad 64->68 keeps 16B alignment, reads 2-way (free)
    __shared__ float Bs[32][68];

    int t = blockIdx.x % NTRI;
    int b = blockIdx.x / NTRI;
    // decode upper-tri tile (i <= j): start(i) = i*(65-i)/2
    int i = (int)((65.0f - sqrtf(4225.0f - 8.0f * (float)t)) * 0.5f);
    if (i > 31) i = 31;
    if (i < 0) i = 0;
    while (i < 31 && ((i + 1) * (65 - (i + 1))) / 2 <= t) ++i;
    while (i > 0 && (i * (65 - i)) / 2 > t) --i;
    int j = i + (t - (i * (65 - i)) / 2);
    int n0 = i << 6, m0 = j << 6;

    int tid  = threadIdx.x;
    int lrow = tid & 63;              // loader: row within tile
    int lc   = (tid >> 6) << 3;       // loader: k-offset 0/8/16/24
    int tm   = tid & 15;              // compute: 16x16 threads, 4x4 micro-tile
    int tn   = tid >> 4;

    float acc[4][4] = {{0.f}};

    for (int kc = 0; kc < 48; ++kc) {            // 48 chunks of BK=32 over F=1536
        int tt = kc >> 2;
        int d0 = (kc & 3) << 5;
        const float* base = x + ((((size_t)tt * BB + b) * NN) << 7) + d0;
        float4 a0 = *(const float4*)(base + ((size_t)(n0 + lrow) << 7) + lc);
        float4 a1 = *(const float4*)(base + ((size_t)(n0 + lrow) << 7) + lc + 4);
        float4 b0 = *(const float4*)(base + ((size_t)(m0 + lrow) << 7) + lc);
        float4 b1 = *(const float4*)(base + ((size_t)(m0 + lrow) << 7) + lc + 4);

        __syncthreads();   // previous iteration's reads done
        As[lc + 0][lrow] = a0.x; As[lc + 1][lrow] = a0.y;
        As[lc + 2][lrow] = a0.z; As[lc + 3][lrow] = a0.w;
        As[lc + 4][lrow] = a1.x; As[lc + 5][lrow] = a1.y;
        As[lc + 6][lrow] = a1.z; As[lc + 7][lrow] = a1.w;
        Bs[lc + 0][lrow] = b0.x; Bs[lc + 1][lrow] = b0.y;
        Bs[lc + 2][lrow] = b0.z; Bs[lc + 3][lrow] = b0.w;
        Bs[lc + 4][lrow] = b1.x; Bs[lc + 5][lrow] = b1.y;
        Bs[lc + 6][lrow] = b1.z; Bs[lc + 7][lrow] = b1.w;
        __syncthreads();

#pragma unroll
        for (int kk = 0; kk < 32; ++kk) {
            float4 af = *(const float4*)&As[kk][tm << 2];
            float4 bf = *(const float4*)&Bs[kk][tn << 2];
            float a_[4] = {af.x, af.y, af.z, af.w};
            float b_[4] = {bf.x, bf.y, bf.z, bf.w};
#pragma unroll
            for (int r = 0; r < 4; ++r)
#pragma unroll
                for (int c = 0; c < 4; ++c) acc[r][c] += a_[r] * b_[c];
        }
    }

    // epilogue: cosine scaling, write tile and its transpose
    float rn[4], rm[4];
#pragma unroll
    for (int r = 0; r < 4; ++r) rn[r] = invn[(b << 11) + n0 + (tm << 2) + r];
#pragma unroll
    for (int c = 0; c < 4; ++c) rm[c] = invn[(b << 11) + m0 + (tn << 2) + c];
#pragma unroll
    for (int r = 0; r < 4; ++r)
#pragma unroll
        for (int c = 0; c < 4; ++c) acc[r][c] *= rn[r] * rm[c];

    float* outb = dist + ((size_t)b << 22);
#pragma unroll
    for (int r = 0; r < 4; ++r) {
        float4 v = make_float4(acc[r][0], acc[r][1], acc[r][2], acc[r][3]);
        *(float4*)(outb + ((size_t)(n0 + (tm << 2) + r) << 11) + m0 + (tn << 2)) = v;
    }
    if (i != j) {
#pragma unroll
        for (int c = 0; c < 4; ++c) {
            float4 v = make_float4(acc[0][c], acc[1][c], acc[2][c], acc[3][c]);
            *(float4*)(outb + ((size_t)(m0 + (tn << 2) + c) << 11) + n0 + (tm << 2)) = v;
        }
    }
}

// ---------------- 3) per-row stable top-5 over the dist row (one wave per row)
__global__ __launch_bounds__(256) void topk_kernel(const float* __restrict__ dist,
                                                   float* __restrict__ tv,
                                                   int* __restrict__ ti) {
    __shared__ float sv[4][64 * KTOP];
    __shared__ int   si[4][64 * KTOP];
    int wave = threadIdx.x >> 6, lane = threadIdx.x & 63;
    int row  = (blockIdx.x << 2) + wave;
    const float* p = dist + ((size_t)row << 11);

    float bv[KTOP]; int bi[KTOP];
#pragma unroll
    for (int k = 0; k < KTOP; ++k) { bv[k] = -3.0e38f; bi[k] = 1 << 30; }
    for (int it = 0; it < 8; ++it) {
        int m = (((it << 6) + lane) << 2);
        float4 v = *(const float4*)(p + m);
        tk_insert(bv, bi, v.x, m);
        tk_insert(bv, bi, v.y, m + 1);
        tk_insert(bv, bi, v.z, m + 2);
        tk_insert(bv, bi, v.w, m + 3);
    }
#pragma unroll
    for (int k = 0; k < KTOP; ++k) { sv[wave][lane * KTOP + k] = bv[k]; si[wave][lane * KTOP + k] = bi[k]; }
    __syncthreads();
    if ((lane & 7) == 0) {   // first-level merge: 8 lanes' lists each
        float mv[KTOP]; int mi[KTOP];
#pragma unroll
        for (int k = 0; k < KTOP; ++k) { mv[k] = -3.0e38f; mi[k] = 1 << 30; }
        for (int l = lane; l < lane + 8; ++l)
            for (int k = 0; k < KTOP; ++k)
                tk_insert(mv, mi, sv[wave][l * KTOP + k], si[wave][l * KTOP + k]);
#pragma unroll
        for (int k = 0; k < KTOP; ++k) { sv[wave][lane * KTOP + k] = mv[k]; si[wave][lane * KTOP + k] = mi[k]; }
    }
    __syncthreads();
    if (lane == 0) {
        float mv[KTOP]; int mi[KTOP];
#pragma unroll
        for (int k = 0; k < KTOP; ++k) { mv[k] = -3.0e38f; mi[k] = 1 << 30; }
        for (int l = 0; l < 64; l += 8)
            for (int k = 0; k < KTOP; ++k)
                tk_insert(mv, mi, sv[wave][l * KTOP + k], si[wave][l * KTOP + k]);
#pragma unroll
        for (int k = 0; k < KTOP; ++k) { tv[row * KTOP + k] = mv[k]; ti[row * KTOP + k] = mi[k]; }
    }
}

// ---------------- 4) scatter: out[b][n][m] += leaky(v)*0.5, and transpose position
__global__ __launch_bounds__(256) void scatter_kernel(const float* __restrict__ tv,
                                                      const int* __restrict__ ti,
                                                      float* __restrict__ out) {
    int g = blockIdx.x * 256 + threadIdx.x;       // < 32768 * 5
    if (g >= NROWS * KTOP) return;
    int row = g / KTOP;
    int b = row >> 11, n = row & (NN - 1);
    float v = tv[g];
    int m = ti[g];
    float a = (v >= 0.0f ? v : 0.01f * v) * 0.5f;
    float* base = out + ((size_t)b << 22);
    atomicAdd(base + ((size_t)n << 11) + m, a);
    atomicAdd(base + ((size_t)m << 11) + n, a);
}

extern "C" void kernel_launch(void* const* d_in, const int* in_sizes, int n_in,
                              void* d_out, int out_size, void* d_ws, size_t ws_size,
                              hipStream_t stream) {
    const float* x = (const float*)d_in[0];
    float* out = (float*)d_out;

    // workspace layout: invnorm[32768] | topk vals[32768*5] | topk idx[32768*5]  (~1.4 MB)
    float* invn = (float*)d_ws;
    float* tv   = invn + NROWS;
    int*   ti   = (int*)(tv + NROWS * KTOP);

    norms_kernel<<<NROWS / 4, 256, 0, stream>>>(x, invn);
    gemm_kernel<<<NTRI * BB, 256, 0, stream>>>(x, invn, out);     // d_out as dist scratch
    topk_kernel<<<NROWS / 4, 256, 0, stream>>>(out, tv, ti);
    hipMemsetAsync(d_out, 0, (size_t)out_size * sizeof(float), stream);
    scatter_kernel<<<(NROWS * KTOP + 255) / 256, 256, 0, stream>>>(tv, ti, out);
}